// Round 1
// baseline (588.429 us; speedup 1.0000x reference)
//
#include <hip/hip_runtime.h>
#include <hip/hip_bf16.h>
#include <stdint.h>

// Problem dims (fixed for this problem instance)
#define MD 8192
#define ND 4096
#define KD 4096
#define RD 32

typedef __bf16 bf16x8 __attribute__((ext_vector_type(8)));
typedef float f32x4 __attribute__((ext_vector_type(4)));

// async 16B global->LDS (wave-uniform LDS base + lane*16 scatter)
__device__ __forceinline__ void cp16(const void* g, void* l) {
    __builtin_amdgcn_global_load_lds(
        (const __attribute__((address_space(1))) void*)g,
        (__attribute__((address_space(3))) void*)l, 16, 0, 0);
}

// ---------------------------------------------------------------------------
// Kernel 1: x fp32 -> bf16  (8 elems/thread, 16B stores)
// ---------------------------------------------------------------------------
__global__ __launch_bounds__(256) void cvt_x(const float* __restrict__ x,
                                             __hip_bfloat16* __restrict__ y) {
    size_t i = ((size_t)blockIdx.x * 256 + threadIdx.x) * 8;
    float4 a = *(const float4*)(x + i);
    float4 b = *(const float4*)(x + i + 4);
    union { __hip_bfloat16 h[8]; uint4 u; } o;
    o.h[0] = __float2bfloat16(a.x); o.h[1] = __float2bfloat16(a.y);
    o.h[2] = __float2bfloat16(a.z); o.h[3] = __float2bfloat16(a.w);
    o.h[4] = __float2bfloat16(b.x); o.h[5] = __float2bfloat16(b.y);
    o.h[6] = __float2bfloat16(b.z); o.h[7] = __float2bfloat16(b.w);
    *(uint4*)(y + i) = o.u;
}

// ---------------------------------------------------------------------------
// Kernel 2: W_eff[n][k] = dequant_int4(qw, wscales) + wtscale * (pu @ pd)
// tile: 64 n x 128 k per block, 256 threads; thread = 4n x 8k
// ---------------------------------------------------------------------------
__global__ __launch_bounds__(256) void build_weff(
    const int* __restrict__ qw,        // [N][K/2] two nibbles per int
    const float* __restrict__ wsc,     // [K/64][N]
    const float* __restrict__ pd,      // [R][K]
    const float* __restrict__ pu,      // [N][R]
    const float* __restrict__ wts_p,   // [1]
    __hip_bfloat16* __restrict__ weff) // [N][K]
{
    __shared__ float pd_s[RD][132];
    __shared__ float pu_t[RD][68];
    const int t = threadIdx.x;
    const int kb = blockIdx.x * 128;
    const int nb = blockIdx.y * 64;

    for (int f = t; f < (RD * 128) / 4; f += 256) {
        int r = f >> 5;
        int c = (f & 31) << 2;
        *(float4*)&pd_s[r][c] = *(const float4*)(pd + (size_t)r * KD + kb + c);
    }
    for (int f = t; f < (64 * RD) / 4; f += 256) {
        int nl = f >> 3;
        int r4 = (f & 7) << 2;
        float4 v = *(const float4*)(pu + (size_t)(nb + nl) * RD + r4);
        pu_t[r4 + 0][nl] = v.x; pu_t[r4 + 1][nl] = v.y;
        pu_t[r4 + 2][nl] = v.z; pu_t[r4 + 3][nl] = v.w;
    }
    __syncthreads();

    const float wts = wts_p[0];
    const int kc = (t & 15) << 3;   // local k base (8 cols)
    const int ng = (t >> 4) << 2;   // local n base (4 rows)

    float acc[4][8];
#pragma unroll
    for (int i = 0; i < 4; ++i)
#pragma unroll
        for (int j = 0; j < 8; ++j) acc[i][j] = 0.f;

    for (int r = 0; r < RD; ++r) {
        float4 pda = *(const float4*)&pd_s[r][kc];
        float4 pdb = *(const float4*)&pd_s[r][kc + 4];
        float4 puv = *(const float4*)&pu_t[r][ng];
        float pus[4] = {puv.x, puv.y, puv.z, puv.w};
        float pdv[8] = {pda.x, pda.y, pda.z, pda.w, pdb.x, pdb.y, pdb.z, pdb.w};
#pragma unroll
        for (int i = 0; i < 4; ++i)
#pragma unroll
            for (int j = 0; j < 8; ++j)
                acc[i][j] += pus[i] * pdv[j];
    }

    const int kg = kb + kc;
    const int g = kg >> 6;
#pragma unroll
    for (int i = 0; i < 4; ++i) {
        const int n = nb + ng + i;
        const float sc = wsc[(size_t)g * ND + n];
        int4 q = *(const int4*)(qw + (size_t)n * (KD / 2) + (kg >> 1));
        const int qi[4] = {q.x, q.y, q.z, q.w};
        union { __hip_bfloat16 h[8]; uint4 u; } o;
#pragma unroll
        for (int j = 0; j < 4; ++j) {
            const int lo = (qi[j] & 15) - 8;
            const int hi = ((qi[j] >> 4) & 15) - 8;
            o.h[2 * j]     = __float2bfloat16((float)lo * sc + wts * acc[i][2 * j]);
            o.h[2 * j + 1] = __float2bfloat16((float)hi * sc + wts * acc[i][2 * j + 1]);
        }
        *(uint4*)(weff + (size_t)n * KD + kg) = o.u;
    }
}

// ---------------------------------------------------------------------------
// Kernel 3: C[M][N] = A[M][K](bf16) * B[N][K](bf16)^T + bias
//
// 256x256 tile, BK=64, 512 threads = 8 waves (2m x 4n), wave owns 128x64.
// 4 phases per K-tile (one C-quadrant x K=64 = 16 MFMA each), raw s_barrier
// + counted vmcnt (never 0 in main loop), per the m201 8-phase template.
//
// Per-wave staging: 8 global_load_lds per K-tile (2/phase), issued in the
// order consumed next K-tile: A-q0 (P1), B-q0 (P2), A-q1 (P3), B-q1 (P4).
// Wait accounting (per wave, all loads its own):
//   P1 end: vmcnt(4) -> completes A-q1 of current tile   (needed by P2 reads)
//   P2 end: vmcnt(4) -> completes B-q1 of current tile   (needed by P3 reads)
//   P3 end: (no wait; P4 data already complete)
//   P4 end: vmcnt(4) -> completes A-q0+B-q0 of next tile (needed by next P1)
// Cross-wave visibility: each consumer reads only after the barrier that
// follows the staging wave's own vmcnt wait. LDS dbuf at K-tile granularity;
// each phase's lgkmcnt(0)+barrier guarantees reads retire before overwrite.
//
// LDS swizzle: row-major [row][64k] in 8x16B chunks, slot = chunk ^ (row&7)
// (verified 0 bank conflicts); global source pre-swizzled so global_load_lds
// dest stays linear (m173). XCD-aware block remap (512 blocks, 512%8==0).
// ---------------------------------------------------------------------------
#define FENCE asm volatile("" ::: "memory")
#define VMW4 asm volatile("s_waitcnt vmcnt(4)" ::: "memory")
#define VMW2 asm volatile("s_waitcnt vmcnt(2)" ::: "memory")
#define VMW0 asm volatile("s_waitcnt vmcnt(0)" ::: "memory")
#define VMNONE
#define ENDB __builtin_amdgcn_s_barrier(); FENCE
#define ENDNONE

#define PHASE(QI, QJ, CB, STAGE, WAITM, ENDM)                                  \
    {                                                                          \
        bf16x8 af[4][2], bfr[2][2];                                            \
        const char* Ab = ArowBase + (CB) + (QI) * 8192;                        \
        const char* Bb = BrowBase + (CB) + (QJ) * 4096;                        \
        _Pragma("unroll") for (int i = 0; i < 4; ++i) {                        \
            af[i][0] = *(const bf16x8*)(Ab + i * 2048 + slh0);                 \
            af[i][1] = *(const bf16x8*)(Ab + i * 2048 + slh1);                 \
        }                                                                      \
        _Pragma("unroll") for (int j = 0; j < 2; ++j) {                        \
            bfr[j][0] = *(const bf16x8*)(Bb + j * 2048 + slh0);                \
            bfr[j][1] = *(const bf16x8*)(Bb + j * 2048 + slh1);               \
        }                                                                      \
        STAGE;                                                                 \
        WAITM;                                                                 \
        __builtin_amdgcn_s_barrier();                                          \
        asm volatile("s_waitcnt lgkmcnt(0)" ::: "memory");                     \
        __builtin_amdgcn_sched_barrier(0);                                     \
        __builtin_amdgcn_s_setprio(1);                                         \
        _Pragma("unroll") for (int i = 0; i < 4; ++i)                          \
            _Pragma("unroll") for (int j = 0; j < 2; ++j) {                    \
                acc[(QI) * 4 + i][(QJ) * 2 + j] =                              \
                    __builtin_amdgcn_mfma_f32_16x16x32_bf16(                   \
                        af[i][0], bfr[j][0], acc[(QI) * 4 + i][(QJ) * 2 + j],  \
                        0, 0, 0);                                              \
                acc[(QI) * 4 + i][(QJ) * 2 + j] =                              \
                    __builtin_amdgcn_mfma_f32_16x16x32_bf16(                   \
                        af[i][1], bfr[j][1], acc[(QI) * 4 + i][(QJ) * 2 + j],  \
                        0, 0, 0);                                              \
            }                                                                  \
        __builtin_amdgcn_s_setprio(0);                                         \
        ENDM;                                                                  \
    }

__global__ __launch_bounds__(512, 2) void gemm_bt_bias(
    const __hip_bfloat16* __restrict__ A,  // [M][K]
    const __hip_bfloat16* __restrict__ B,  // [N][K]
    const float* __restrict__ bias,        // [N]
    float* __restrict__ C)                 // [M][N]
{
    __shared__ alignas(16) char As[2][32768]; // [dbuf][256 rows][64 k] bf16
    __shared__ alignas(16) char Bs[2][32768];

    const int t = threadIdx.x;
    const int lane = t & 63;
    const int w = t >> 6;        // wave 0..7
    const int wm = w >> 2;       // 0..1  (m)
    const int wn = w & 3;        // 0..3  (n)

    // XCD-aware remap: 512 blocks = 32 m-tiles x 16 n-tiles; each XCD gets
    // a contiguous 4x16 sub-grid (A-panel reuse in its private L2).
    const int bid = blockIdx.x;
    const int swz = (bid & 7) * 64 + (bid >> 3);
    const int m0 = (swz >> 4) * 256;
    const int n0 = (swz & 15) * 256;

    // staging lane geometry: one load = 8 rows x 128B; lane -> (row, slot),
    // global chunk pre-swizzled: gch = slot ^ (row&7)
    const int lrow = lane >> 3;
    const int gch = (lane & 7) ^ lrow;
    const __hip_bfloat16* Ag = A + (size_t)(m0 + lrow) * KD + gch * 8;
    const __hip_bfloat16* Bg = B + (size_t)(n0 + lrow) * KD + gch * 8;

    // per-wave 8-row block ids (disjoint cover of 32 A-blocks / 32 B-blocks)
    const int a1 = w, a2 = 16 + w, a3 = 8 + w, a4 = 24 + w;    // A: q0,q0,q1,q1
    const int bq = wm * 8 + wn;
    const int b1 = bq, b2 = bq + 16, b3 = bq + 4, b4 = bq + 20; // B: q0,q0,q1,q1

    // fragment read geometry (16x16x32 A/B layout: row=lane&15, kchunk=lane>>4)
    const int qm = lane & 15;
    const int c4 = lane >> 4;
    const int slh0 = (c4 ^ (qm & 7)) * 16;        // k-half 0 slot byte off
    const int slh1 = ((4 + c4) ^ (qm & 7)) * 16;  // k-half 1
    const char* ArowBase = (const char*)As + (wm * 128 + qm) * 128;
    const char* BrowBase = (const char*)Bs + (wn * 64 + qm) * 128;

    // prologue: stage K-tile 0 into buf0 in consumption order
    cp16(Ag + (size_t)a1 * 8 * KD, (char*)As + a1 * 1024);
    cp16(Ag + (size_t)a2 * 8 * KD, (char*)As + a2 * 1024);
    cp16(Bg + (size_t)b1 * 8 * KD, (char*)Bs + b1 * 1024);
    cp16(Bg + (size_t)b2 * 8 * KD, (char*)Bs + b2 * 1024);
    cp16(Ag + (size_t)a3 * 8 * KD, (char*)As + a3 * 1024);
    cp16(Ag + (size_t)a4 * 8 * KD, (char*)As + a4 * 1024);
    cp16(Bg + (size_t)b3 * 8 * KD, (char*)Bs + b3 * 1024);
    cp16(Bg + (size_t)b4 * 8 * KD, (char*)Bs + b4 * 1024);

    f32x4 acc[8][4];
#pragma unroll
    for (int i = 0; i < 8; ++i)
#pragma unroll
        for (int j = 0; j < 4; ++j) acc[i][j] = (f32x4){0.f, 0.f, 0.f, 0.f};

    VMW4;                          // A-q0 + B-q0 of tile 0 arrived
    __builtin_amdgcn_s_barrier();
    FENCE;

    for (int kt = 0; kt < 63; ++kt) {
        const int cb = (kt & 1) << 15;   // compute buffer byte offset
        const int sb = cb ^ 32768;       // stage buffer (tile kt+1)
        const size_t ko = (size_t)(kt + 1) * 64;
        PHASE(0, 0, cb,
              (cp16(Ag + (size_t)a1 * 8 * KD + ko, (char*)As + sb + a1 * 1024),
               cp16(Ag + (size_t)a2 * 8 * KD + ko, (char*)As + sb + a2 * 1024)),
              VMW4, ENDB)
        PHASE(1, 0, cb,
              (cp16(Bg + (size_t)b1 * 8 * KD + ko, (char*)Bs + sb + b1 * 1024),
               cp16(Bg + (size_t)b2 * 8 * KD + ko, (char*)Bs + sb + b2 * 1024)),
              VMW4, ENDB)
        PHASE(0, 1, cb,
              (cp16(Ag + (size_t)a3 * 8 * KD + ko, (char*)As + sb + a3 * 1024),
               cp16(Ag + (size_t)a4 * 8 * KD + ko, (char*)As + sb + a4 * 1024)),
              VMNONE, ENDB)
        PHASE(1, 1, cb,
              (cp16(Bg + (size_t)b3 * 8 * KD + ko, (char*)Bs + sb + b3 * 1024),
               cp16(Bg + (size_t)b4 * 8 * KD + ko, (char*)Bs + sb + b4 * 1024)),
              VMW4, ENDB)
    }
    // tail: K-tile 63 in buf1, no staging; drain progressively
    PHASE(0, 0, 32768, ((void)0), VMW2, ENDB)
    PHASE(1, 0, 32768, ((void)0), VMW0, ENDB)
    PHASE(0, 1, 32768, ((void)0), VMNONE, ENDB)
    PHASE(1, 1, 32768, ((void)0), VMNONE, ENDNONE)

    // epilogue: C/D layout col=lane&15, row=(lane>>4)*4+reg
    const int cm = (lane >> 4) << 2;
    const int cn = lane & 15;
#pragma unroll
    for (int j = 0; j < 4; ++j) {
        const int n = n0 + wn * 64 + j * 16 + cn;
        const float bv = bias[n];
#pragma unroll
        for (int i = 0; i < 8; ++i) {
            float* dst = C + (size_t)(m0 + wm * 128 + i * 16 + cm) * ND + n;
#pragma unroll
            for (int r = 0; r < 4; ++r)
                dst[(size_t)r * ND] = acc[i][j][r] + bv;
        }
    }
}

// ---------------------------------------------------------------------------
extern "C" void kernel_launch(void* const* d_in, const int* in_sizes, int n_in,
                              void* d_out, int out_size, void* d_ws, size_t ws_size,
                              hipStream_t stream) {
    const float* x    = (const float*)d_in[0];   // [M][K] fp32
    const int* qw     = (const int*)d_in[1];     // [N][K/2]
    const float* wsc  = (const float*)d_in[2];   // [K/64][N]
    const float* pd   = (const float*)d_in[3];   // [R][K]
    const float* pu   = (const float*)d_in[4];   // [N][R]
    const float* wts  = (const float*)d_in[5];   // [1]
    const float* bias = (const float*)d_in[6];   // [N]
    float* out = (float*)d_out;                  // [M][N] fp32

    __hip_bfloat16* weff = (__hip_bfloat16*)d_ws;
    __hip_bfloat16* xbf  = (__hip_bfloat16*)((char*)d_ws + (size_t)ND * KD * sizeof(__hip_bfloat16));

    cvt_x<<<(MD * (size_t)KD) / (256 * 8), 256, 0, stream>>>(x, xbf);
    build_weff<<<dim3(KD / 128, ND / 64), 256, 0, stream>>>(qw, wsc, pd, pu, wts, weff);
    gemm_bt_bias<<<512, 512, 0, stream>>>(xbf, weff, bias, out);
}

// Round 2
// 553.698 us; speedup vs baseline: 1.0627x; 1.0627x over previous
//
#include <hip/hip_runtime.h>
#include <hip/hip_bf16.h>
#include <stdint.h>

// Problem dims (fixed for this problem instance)
#define MD 8192
#define ND 4096
#define KD 4096
#define RD 32

typedef __bf16 bf16x8 __attribute__((ext_vector_type(8)));
typedef float f32x4 __attribute__((ext_vector_type(4)));

// async 16B global->LDS (wave-uniform LDS base + lane*16 scatter)
__device__ __forceinline__ void cp16(const void* g, void* l) {
    __builtin_amdgcn_global_load_lds(
        (const __attribute__((address_space(1))) void*)g,
        (__attribute__((address_space(3))) void*)l, 16, 0, 0);
}

// ---------------------------------------------------------------------------
// Kernel 1: x fp32 -> bf16  (8 elems/thread, 16B stores)
// ---------------------------------------------------------------------------
__global__ __launch_bounds__(256) void cvt_x(const float* __restrict__ x,
                                             __hip_bfloat16* __restrict__ y) {
    size_t i = ((size_t)blockIdx.x * 256 + threadIdx.x) * 8;
    float4 a = *(const float4*)(x + i);
    float4 b = *(const float4*)(x + i + 4);
    union { __hip_bfloat16 h[8]; uint4 u; } o;
    o.h[0] = __float2bfloat16(a.x); o.h[1] = __float2bfloat16(a.y);
    o.h[2] = __float2bfloat16(a.z); o.h[3] = __float2bfloat16(a.w);
    o.h[4] = __float2bfloat16(b.x); o.h[5] = __float2bfloat16(b.y);
    o.h[6] = __float2bfloat16(b.z); o.h[7] = __float2bfloat16(b.w);
    *(uint4*)(y + i) = o.u;
}

// ---------------------------------------------------------------------------
// Kernel 2: W_eff[n][k] = dequant_int4(qw, wscales) + wtscale * (pu @ pd)
// tile: 64 n x 128 k per block, 256 threads; thread = 4n x 8k
// ---------------------------------------------------------------------------
__global__ __launch_bounds__(256) void build_weff(
    const int* __restrict__ qw,        // [N][K/2] two nibbles per int
    const float* __restrict__ wsc,     // [K/64][N]
    const float* __restrict__ pd,      // [R][K]
    const float* __restrict__ pu,      // [N][R]
    const float* __restrict__ wts_p,   // [1]
    __hip_bfloat16* __restrict__ weff) // [N][K]
{
    __shared__ float pd_s[RD][132];
    __shared__ float pu_t[RD][68];
    const int t = threadIdx.x;
    const int kb = blockIdx.x * 128;
    const int nb = blockIdx.y * 64;

    for (int f = t; f < (RD * 128) / 4; f += 256) {
        int r = f >> 5;
        int c = (f & 31) << 2;
        *(float4*)&pd_s[r][c] = *(const float4*)(pd + (size_t)r * KD + kb + c);
    }
    for (int f = t; f < (64 * RD) / 4; f += 256) {
        int nl = f >> 3;
        int r4 = (f & 7) << 2;
        float4 v = *(const float4*)(pu + (size_t)(nb + nl) * RD + r4);
        pu_t[r4 + 0][nl] = v.x; pu_t[r4 + 1][nl] = v.y;
        pu_t[r4 + 2][nl] = v.z; pu_t[r4 + 3][nl] = v.w;
    }
    __syncthreads();

    const float wts = wts_p[0];
    const int kc = (t & 15) << 3;   // local k base (8 cols)
    const int ng = (t >> 4) << 2;   // local n base (4 rows)

    float acc[4][8];
#pragma unroll
    for (int i = 0; i < 4; ++i)
#pragma unroll
        for (int j = 0; j < 8; ++j) acc[i][j] = 0.f;

    for (int r = 0; r < RD; ++r) {
        float4 pda = *(const float4*)&pd_s[r][kc];
        float4 pdb = *(const float4*)&pd_s[r][kc + 4];
        float4 puv = *(const float4*)&pu_t[r][ng];
        float pus[4] = {puv.x, puv.y, puv.z, puv.w};
        float pdv[8] = {pda.x, pda.y, pda.z, pda.w, pdb.x, pdb.y, pdb.z, pdb.w};
#pragma unroll
        for (int i = 0; i < 4; ++i)
#pragma unroll
            for (int j = 0; j < 8; ++j)
                acc[i][j] += pus[i] * pdv[j];
    }

    const int kg = kb + kc;
    const int g = kg >> 6;
#pragma unroll
    for (int i = 0; i < 4; ++i) {
        const int n = nb + ng + i;
        const float sc = wsc[(size_t)g * ND + n];
        int4 q = *(const int4*)(qw + (size_t)n * (KD / 2) + (kg >> 1));
        const int qi[4] = {q.x, q.y, q.z, q.w};
        union { __hip_bfloat16 h[8]; uint4 u; } o;
#pragma unroll
        for (int j = 0; j < 4; ++j) {
            const int lo = (qi[j] & 15) - 8;
            const int hi = ((qi[j] >> 4) & 15) - 8;
            o.h[2 * j]     = __float2bfloat16((float)lo * sc + wts * acc[i][2 * j]);
            o.h[2 * j + 1] = __float2bfloat16((float)hi * sc + wts * acc[i][2 * j + 1]);
        }
        *(uint4*)(weff + (size_t)n * KD + kg) = o.u;
    }
}

// ---------------------------------------------------------------------------
// Kernel 3: C[M][N] = A[M][K](bf16) * B[N][K](bf16)^T + bias
//
// 256x256 tile, BK=64, 512 threads = 8 waves (2m x 4n), wave owns 128x64.
// Schedule (1 barrier / K-tile, full-tile prefetch distance):
//   per tile k:
//     stage ALL 8 global_load_lds for tile k+1 into sb   (issue at tile top)
//     phase h0: 12 ds_read_b128 (8 A + 4 B, k-half 0); lgkmcnt(0);
//               sched_barrier; setprio(1); 32 MFMA; setprio(0)
//     phase h1: same for k-half 1
//     vmcnt(0)   <- loads have had ~2 full MFMA phases (~2000+ cyc) in
//                   flight, >> HBM latency, so this drain is ~free
//     s_barrier  <- publishes sb (everyone's vmcnt done) AND frees cb
//                   (everyone's reads retired via lgkm before last MFMA)
// Hazards checked: stage writes only sb (!= cb); cb never written during
// tile k; each wave's ds_reads retire before its MFMA (lgkm hammer); the
// single barrier orders both publication and reuse. Waves de-couple within
// a tile (no intra-tile barrier) so one wave's h1 reads overlap another's
// h0 MFMAs.
//
// Every A/B fragment is read exactly once per K-tile (24 ds_read_b128,
// minimal) vs 48 in the 4-phase variant.
//
// LDS swizzle: row-major [row][64k] in 8x16B chunks, slot = chunk ^ (row&7)
// (verified 0 bank conflicts); global source pre-swizzled so global_load_lds
// dest stays linear. XCD-aware block remap (512 blocks, 512%8==0).
// ---------------------------------------------------------------------------
#define FENCE asm volatile("" ::: "memory")

#define PHASEH(CB, SL)                                                         \
    {                                                                          \
        bf16x8 af[8], bf[4];                                                   \
        _Pragma("unroll") for (int i = 0; i < 8; ++i)                          \
            af[i] = *(const bf16x8*)(ArowB + (CB) + i * 2048 + (SL));          \
        _Pragma("unroll") for (int j = 0; j < 4; ++j)                          \
            bf[j] = *(const bf16x8*)(BrowB + (CB) + j * 2048 + (SL));          \
        asm volatile("s_waitcnt lgkmcnt(0)" ::: "memory");                     \
        __builtin_amdgcn_sched_barrier(0);                                     \
        __builtin_amdgcn_s_setprio(1);                                         \
        _Pragma("unroll") for (int i = 0; i < 8; ++i)                          \
            _Pragma("unroll") for (int j = 0; j < 4; ++j)                      \
                acc[i][j] = __builtin_amdgcn_mfma_f32_16x16x32_bf16(           \
                    af[i], bf[j], acc[i][j], 0, 0, 0);                         \
        __builtin_amdgcn_s_setprio(0);                                         \
    }

__global__ __launch_bounds__(512, 2) void gemm_bt_bias(
    const __hip_bfloat16* __restrict__ A,  // [M][K]
    const __hip_bfloat16* __restrict__ B,  // [N][K]
    const float* __restrict__ bias,        // [N]
    float* __restrict__ C)                 // [M][N]
{
    __shared__ alignas(16) char As[2][32768]; // [dbuf][256 rows][64 k] bf16
    __shared__ alignas(16) char Bs[2][32768];

    const int t = threadIdx.x;
    const int lane = t & 63;
    const int w = t >> 6;        // wave 0..7
    const int wm = w >> 2;       // 0..1  (m)
    const int wn = w & 3;        // 0..3  (n)

    // XCD-aware remap: 512 blocks = 32 m-tiles x 16 n-tiles; each XCD gets
    // a contiguous 4x16 sub-grid (A-panel reuse in its private L2).
    const int bid = blockIdx.x;
    const int swz = (bid & 7) * 64 + (bid >> 3);
    const int m0 = (swz >> 4) * 256;
    const int n0 = (swz & 15) * 256;

    // staging lane geometry: one load = 8 rows x 128B; lane -> (row, slot),
    // global chunk pre-swizzled: gch = slot ^ (row&7)
    const int lrow = lane >> 3;
    const int gch = (lane & 7) ^ lrow;
    const __hip_bfloat16* Ag = A + (size_t)(m0 + lrow) * KD + gch * 8;
    const __hip_bfloat16* Bg = B + (size_t)(n0 + lrow) * KD + gch * 8;

    // fragment read geometry (16x16x32 A/B layout: row=lane&15, kchunk=lane>>4)
    const int qm = lane & 15;
    const int c4 = lane >> 4;
    const int slh0 = (c4 ^ (qm & 7)) * 16;        // k-half 0 slot byte off
    const int slh1 = ((4 + c4) ^ (qm & 7)) * 16;  // k-half 1
    const char* ArowB = (const char*)As + (wm * 128 + qm) * 128;
    const char* BrowB = (const char*)Bs + (wn * 64 + qm) * 128;

    f32x4 acc[8][4];
#pragma unroll
    for (int i = 0; i < 8; ++i)
#pragma unroll
        for (int j = 0; j < 4; ++j) acc[i][j] = (f32x4){0.f, 0.f, 0.f, 0.f};

    // prologue: stage K-tile 0 into buf0 (wave w owns 8-row blocks w+8q)
#pragma unroll
    for (int q = 0; q < 4; ++q) {
        const int blk = w + 8 * q;
        cp16(Ag + (size_t)blk * 8 * KD, (char*)As + blk * 1024);
        cp16(Bg + (size_t)blk * 8 * KD, (char*)Bs + blk * 1024);
    }
    asm volatile("s_waitcnt vmcnt(0)" ::: "memory");
    __builtin_amdgcn_s_barrier();
    FENCE;

    for (int kt = 0; kt < 63; ++kt) {
        const int cb = (kt & 1) << 15;   // compute buffer byte offset
        const int sb = cb ^ 32768;       // stage buffer (tile kt+1)
        const size_t ko = (size_t)(kt + 1) * 64;
        // stage full tile kt+1 now: issue-to-wait distance = 2 MFMA phases
#pragma unroll
        for (int q = 0; q < 4; ++q) {
            const int blk = w + 8 * q;
            cp16(Ag + (size_t)blk * 8 * KD + ko, (char*)As + sb + blk * 1024);
            cp16(Bg + (size_t)blk * 8 * KD + ko, (char*)Bs + sb + blk * 1024);
        }
        PHASEH(cb, slh0)
        PHASEH(cb, slh1)
        asm volatile("s_waitcnt vmcnt(0)" ::: "memory");
        __builtin_amdgcn_s_barrier();
        FENCE;
    }
    // tail: K-tile 63 in buf1, no staging, no trailing barrier
    PHASEH(32768, slh0)
    PHASEH(32768, slh1)

    // epilogue: C/D layout col=lane&15, row=(lane>>4)*4+reg
    const int cm = (lane >> 4) << 2;
    const int cn = lane & 15;
#pragma unroll
    for (int j = 0; j < 4; ++j) {
        const int n = n0 + wn * 64 + j * 16 + cn;
        const float bv = bias[n];
#pragma unroll
        for (int i = 0; i < 8; ++i) {
            float* dst = C + (size_t)(m0 + wm * 128 + i * 16 + cm) * ND + n;
#pragma unroll
            for (int r = 0; r < 4; ++r)
                dst[(size_t)r * ND] = acc[i][j][r] + bv;
        }
    }
}

// ---------------------------------------------------------------------------
extern "C" void kernel_launch(void* const* d_in, const int* in_sizes, int n_in,
                              void* d_out, int out_size, void* d_ws, size_t ws_size,
                              hipStream_t stream) {
    const float* x    = (const float*)d_in[0];   // [M][K] fp32
    const int* qw     = (const int*)d_in[1];     // [N][K/2]
    const float* wsc  = (const float*)d_in[2];   // [K/64][N]
    const float* pd   = (const float*)d_in[3];   // [R][K]
    const float* pu   = (const float*)d_in[4];   // [N][R]
    const float* wts  = (const float*)d_in[5];   // [1]
    const float* bias = (const float*)d_in[6];   // [N]
    float* out = (float*)d_out;                  // [M][N] fp32

    __hip_bfloat16* weff = (__hip_bfloat16*)d_ws;
    __hip_bfloat16* xbf  = (__hip_bfloat16*)((char*)d_ws + (size_t)ND * KD * sizeof(__hip_bfloat16));

    cvt_x<<<(MD * (size_t)KD) / (256 * 8), 256, 0, stream>>>(x, xbf);
    build_weff<<<dim3(KD / 128, ND / 64), 256, 0, stream>>>(qw, wsc, pd, pu, wts, weff);
    gemm_bt_bias<<<512, 512, 0, stream>>>(xbf, weff, bias, out);
}

// Round 3
// 515.732 us; speedup vs baseline: 1.1410x; 1.0736x over previous
//
#include <hip/hip_runtime.h>
#include <hip/hip_bf16.h>
#include <stdint.h>

// Problem dims (fixed for this problem instance)
#define MD 8192
#define ND 4096
#define KD 4096
#define RD 32

typedef __bf16 bf16x8 __attribute__((ext_vector_type(8)));
typedef float f32x4 __attribute__((ext_vector_type(4)));

// async 16B global->LDS (wave-uniform LDS base + lane*16 scatter)
__device__ __forceinline__ void cp16(const void* g, void* l) {
    __builtin_amdgcn_global_load_lds(
        (const __attribute__((address_space(1))) void*)g,
        (__attribute__((address_space(3))) void*)l, 16, 0, 0);
}

// ---------------------------------------------------------------------------
// Kernel 1: x fp32 -> bf16  (8 elems/thread, 16B stores)
// ---------------------------------------------------------------------------
__global__ __launch_bounds__(256) void cvt_x(const float* __restrict__ x,
                                             __hip_bfloat16* __restrict__ y) {
    size_t i = ((size_t)blockIdx.x * 256 + threadIdx.x) * 8;
    float4 a = *(const float4*)(x + i);
    float4 b = *(const float4*)(x + i + 4);
    union { __hip_bfloat16 h[8]; uint4 u; } o;
    o.h[0] = __float2bfloat16(a.x); o.h[1] = __float2bfloat16(a.y);
    o.h[2] = __float2bfloat16(a.z); o.h[3] = __float2bfloat16(a.w);
    o.h[4] = __float2bfloat16(b.x); o.h[5] = __float2bfloat16(b.y);
    o.h[6] = __float2bfloat16(b.z); o.h[7] = __float2bfloat16(b.w);
    *(uint4*)(y + i) = o.u;
}

// ---------------------------------------------------------------------------
// Kernel 2: W_eff[n][k] = dequant_int4(qw, wscales) + wtscale * (pu @ pd)
// tile: 64 n x 128 k per block, 256 threads; thread = 4n x 8k
// ---------------------------------------------------------------------------
__global__ __launch_bounds__(256) void build_weff(
    const int* __restrict__ qw,        // [N][K/2] two nibbles per int
    const float* __restrict__ wsc,     // [K/64][N]
    const float* __restrict__ pd,      // [R][K]
    const float* __restrict__ pu,      // [N][R]
    const float* __restrict__ wts_p,   // [1]
    __hip_bfloat16* __restrict__ weff) // [N][K]
{
    __shared__ float pd_s[RD][132];
    __shared__ float pu_t[RD][68];
    const int t = threadIdx.x;
    const int kb = blockIdx.x * 128;
    const int nb = blockIdx.y * 64;

    for (int f = t; f < (RD * 128) / 4; f += 256) {
        int r = f >> 5;
        int c = (f & 31) << 2;
        *(float4*)&pd_s[r][c] = *(const float4*)(pd + (size_t)r * KD + kb + c);
    }
    for (int f = t; f < (64 * RD) / 4; f += 256) {
        int nl = f >> 3;
        int r4 = (f & 7) << 2;
        float4 v = *(const float4*)(pu + (size_t)(nb + nl) * RD + r4);
        pu_t[r4 + 0][nl] = v.x; pu_t[r4 + 1][nl] = v.y;
        pu_t[r4 + 2][nl] = v.z; pu_t[r4 + 3][nl] = v.w;
    }
    __syncthreads();

    const float wts = wts_p[0];
    const int kc = (t & 15) << 3;   // local k base (8 cols)
    const int ng = (t >> 4) << 2;   // local n base (4 rows)

    float acc[4][8];
#pragma unroll
    for (int i = 0; i < 4; ++i)
#pragma unroll
        for (int j = 0; j < 8; ++j) acc[i][j] = 0.f;

    for (int r = 0; r < RD; ++r) {
        float4 pda = *(const float4*)&pd_s[r][kc];
        float4 pdb = *(const float4*)&pd_s[r][kc + 4];
        float4 puv = *(const float4*)&pu_t[r][ng];
        float pus[4] = {puv.x, puv.y, puv.z, puv.w};
        float pdv[8] = {pda.x, pda.y, pda.z, pda.w, pdb.x, pdb.y, pdb.z, pdb.w};
#pragma unroll
        for (int i = 0; i < 4; ++i)
#pragma unroll
            for (int j = 0; j < 8; ++j)
                acc[i][j] += pus[i] * pdv[j];
    }

    const int kg = kb + kc;
    const int g = kg >> 6;
#pragma unroll
    for (int i = 0; i < 4; ++i) {
        const int n = nb + ng + i;
        const float sc = wsc[(size_t)g * ND + n];
        int4 q = *(const int4*)(qw + (size_t)n * (KD / 2) + (kg >> 1));
        const int qi[4] = {q.x, q.y, q.z, q.w};
        union { __hip_bfloat16 h[8]; uint4 u; } o;
#pragma unroll
        for (int j = 0; j < 4; ++j) {
            const int lo = (qi[j] & 15) - 8;
            const int hi = ((qi[j] >> 4) & 15) - 8;
            o.h[2 * j]     = __float2bfloat16((float)lo * sc + wts * acc[i][2 * j]);
            o.h[2 * j + 1] = __float2bfloat16((float)hi * sc + wts * acc[i][2 * j + 1]);
        }
        *(uint4*)(weff + (size_t)n * KD + kg) = o.u;
    }
}

// ---------------------------------------------------------------------------
// Kernel 3: C[M][N] = A[M][K](bf16) * B[N][K](bf16)^T + bias
//
// 256x256 tile, BK=64, 512 threads = 8 waves (2m x 4n), wave owns 128x64.
// m201-style 4-phase/K-tile schedule, 16 MFMA per lgkm-drain, 24 ds_read
// per tile (minimal: every fragment read once), counted vmcnt never 0.
//
// Phase p: {ds_read batch; 2 cp16 stage; [vmcnt(4)]; barrier; lgkmcnt(0)+
//           sched_barrier; setprio(1); 16 MFMA (one quadrant x K=64);
//           setprio(0)}
//   P1: read af0 (A i0-3, 8) + bf j0 (4); stage A-set1; vmcnt(4); Q(0,0)
//   P2: read af1 (A i4-7, 8);             stage B-set2; vmcnt(4); Q(1,0)
//   P3: read bf j1 (4);                   stage A-set3;           Q(1,1)
//   P4: (no reads);                       stage B-set4; vmcnt(4); Q(0,1)
//
// Stage sets (16 8-row blocks/phase; wave w stages 2):
//   set1: A blocks {w, 16+w}        = rows read by next-P1 af0 (both wm)
//   set2: B blocks {bp2a, bp2a+16}  = rows read by next-P1 bf j0 (all wn)
//   set3: A blocks {8+w, 24+w}      = next-P2 af1 rows
//   set4: B blocks {bp2a+4, +20}    = next-P3 bf j1 rows
// FIFO vmcnt ledger (per wave, 2 loads/phase; invariant at tile start:
// outstanding = {prev set3, prev set4}):
//   P1 vmcnt(4): drains prev-set3  -> covers this-P2 reads (2-phase dist)
//   P2 vmcnt(4): drains prev-set4  -> covers this-P3 reads (3-phase dist)
//   P4 vmcnt(4): drains set1+set2  -> covers next-P1 reads (2-3 phase dist)
// Each wait's youngest covered load issued >=2 phases (~1300 cy) earlier ->
// waits ~free; 4-8 loads always in flight. Barrier after each vmcnt
// publishes staged data cross-wave before the reads that need it.
// cb-overwrite hazard: tile t reads of cb retire at each phase's lgkm(0),
// >=4 barriers before tile t+2's stages touch that buffer.
//
// LDS swizzle: row-major [row][64k] in 8x16B chunks, slot = chunk ^ (row&7)
// (verified 0 bank conflicts); global source pre-swizzled so global_load_lds
// dest stays linear. XCD-aware block remap (512 blocks, 512%8==0).
// ---------------------------------------------------------------------------
#define FENCE asm volatile("" ::: "memory")
#define BAR __builtin_amdgcn_s_barrier()
#define VMC(N) asm volatile("s_waitcnt vmcnt(" #N ")" ::: "memory")
#define LGKM0                                                \
    asm volatile("s_waitcnt lgkmcnt(0)" ::: "memory");       \
    __builtin_amdgcn_sched_barrier(0)

#define RD_AF(DST, G, CB)                                                      \
    _Pragma("unroll") for (int i = 0; i < 4; ++i) {                            \
        DST[i][0] = *(const bf16x8*)(ArowB + (CB) + ((G)*4 + i) * 2048 + slh0);\
        DST[i][1] = *(const bf16x8*)(ArowB + (CB) + ((G)*4 + i) * 2048 + slh1);\
    }
#define RD_BF(DST, G, CB)                                                      \
    _Pragma("unroll") for (int j = 0; j < 2; ++j) {                            \
        DST[j][0] = *(const bf16x8*)(BrowB + (CB) + ((G)*2 + j) * 2048 + slh0);\
        DST[j][1] = *(const bf16x8*)(BrowB + (CB) + ((G)*2 + j) * 2048 + slh1);\
    }
#define MFMAQ(MQ, NQ, AF, BF)                                                  \
    __builtin_amdgcn_s_setprio(1);                                             \
    _Pragma("unroll") for (int i = 0; i < 4; ++i)                              \
        _Pragma("unroll") for (int j = 0; j < 2; ++j) {                        \
            acc[(MQ)*4 + i][(NQ)*2 + j] =                                      \
                __builtin_amdgcn_mfma_f32_16x16x32_bf16(                       \
                    AF[i][0], BF[j][0], acc[(MQ)*4 + i][(NQ)*2 + j], 0, 0, 0); \
            acc[(MQ)*4 + i][(NQ)*2 + j] =                                      \
                __builtin_amdgcn_mfma_f32_16x16x32_bf16(                       \
                    AF[i][1], BF[j][1], acc[(MQ)*4 + i][(NQ)*2 + j], 0, 0, 0); \
        }                                                                      \
    __builtin_amdgcn_s_setprio(0)

__global__ __launch_bounds__(512, 2) void gemm_bt_bias(
    const __hip_bfloat16* __restrict__ A,  // [M][K]
    const __hip_bfloat16* __restrict__ B,  // [N][K]
    const float* __restrict__ bias,        // [N]
    float* __restrict__ C)                 // [M][N]
{
    __shared__ alignas(16) char As[2][32768]; // [dbuf][256 rows][64 k] bf16
    __shared__ alignas(16) char Bs[2][32768];

    const int t = threadIdx.x;
    const int lane = t & 63;
    const int w = t >> 6;        // wave 0..7
    const int wm = w >> 2;       // 0..1  (m)
    const int wn = w & 3;        // 0..3  (n)

    // XCD-aware remap: 512 blocks = 32 m-tiles x 16 n-tiles.
    const int bid = blockIdx.x;
    const int swz = (bid & 7) * 64 + (bid >> 3);
    const int m0 = (swz >> 4) * 256;
    const int n0 = (swz & 15) * 256;

    // staging lane geometry: one load = 8 rows x 128B; lane -> (row, slot),
    // global chunk pre-swizzled: gch = slot ^ (row&7)
    const int lrow = lane >> 3;
    const int gch = (lane & 7) ^ lrow;
    const __hip_bfloat16* Ag = A + (size_t)(m0 + lrow) * KD + gch * 8;
    const __hip_bfloat16* Bg = B + (size_t)(n0 + lrow) * KD + gch * 8;

    // per-wave stage block ids
    const int ap1a = w,      ap1b = 16 + w;   // set1 (A, next-P1)
    const int bp2a = (w & 3) + ((w >> 2) << 3);
    const int bp2b = bp2a + 16;               // set2 (B, next-P1)
    const int ap3a = 8 + w,  ap3b = 24 + w;   // set3 (A, next-P2)
    const int bp4a = bp2a + 4, bp4b = bp2b + 4; // set4 (B, next-P3)

    // fragment read geometry (16x16x32 A/B layout: row=lane&15, kchunk=lane>>4)
    const int qm = lane & 15;
    const int c4 = lane >> 4;
    const int slh0 = (c4 ^ (qm & 7)) * 16;        // k-half 0 slot byte off
    const int slh1 = ((4 + c4) ^ (qm & 7)) * 16;  // k-half 1
    const char* ArowB = (const char*)As + (wm * 128 + qm) * 128;
    const char* BrowB = (const char*)Bs + (wn * 64 + qm) * 128;

    f32x4 acc[8][4];
#pragma unroll
    for (int i = 0; i < 8; ++i)
#pragma unroll
        for (int j = 0; j < 4; ++j) acc[i][j] = (f32x4){0.f, 0.f, 0.f, 0.f};

    // prologue: stage K-tile 0 into buf0 in set order (FIFO ledger invariant)
    cp16(Ag + (size_t)ap1a * 8 * KD, (char*)As + ap1a * 1024);
    cp16(Ag + (size_t)ap1b * 8 * KD, (char*)As + ap1b * 1024);
    cp16(Bg + (size_t)bp2a * 8 * KD, (char*)Bs + bp2a * 1024);
    cp16(Bg + (size_t)bp2b * 8 * KD, (char*)Bs + bp2b * 1024);
    cp16(Ag + (size_t)ap3a * 8 * KD, (char*)As + ap3a * 1024);
    cp16(Ag + (size_t)ap3b * 8 * KD, (char*)As + ap3b * 1024);
    cp16(Bg + (size_t)bp4a * 8 * KD, (char*)Bs + bp4a * 1024);
    cp16(Bg + (size_t)bp4b * 8 * KD, (char*)Bs + bp4b * 1024);
    VMC(4);                     // set1+set2 landed (tile-0 P1 data)
    BAR;
    FENCE;

    for (int kt = 0; kt < 63; ++kt) {
        const int cb = (kt & 1) << 15;   // compute buffer byte offset
        const int sb = cb ^ 32768;       // stage buffer (tile kt+1)
        const size_t ko = (size_t)(kt + 1) * 64;
        bf16x8 af0[4][2], af1[4][2], bf[2][2];
        // ---- P1: Q(0,0)
        RD_AF(af0, 0, cb)
        RD_BF(bf, 0, cb)
        cp16(Ag + (size_t)ap1a * 8 * KD + ko, (char*)As + sb + ap1a * 1024);
        cp16(Ag + (size_t)ap1b * 8 * KD + ko, (char*)As + sb + ap1b * 1024);
        VMC(4);
        BAR;
        LGKM0;
        MFMAQ(0, 0, af0, bf);
        // ---- P2: Q(1,0)
        RD_AF(af1, 1, cb)
        cp16(Bg + (size_t)bp2a * 8 * KD + ko, (char*)Bs + sb + bp2a * 1024);
        cp16(Bg + (size_t)bp2b * 8 * KD + ko, (char*)Bs + sb + bp2b * 1024);
        VMC(4);
        BAR;
        LGKM0;
        MFMAQ(1, 0, af1, bf);
        // ---- P3: Q(1,1)
        RD_BF(bf, 1, cb)
        cp16(Ag + (size_t)ap3a * 8 * KD + ko, (char*)As + sb + ap3a * 1024);
        cp16(Ag + (size_t)ap3b * 8 * KD + ko, (char*)As + sb + ap3b * 1024);
        FENCE;
        BAR;
        LGKM0;
        MFMAQ(1, 1, af1, bf);
        // ---- P4: Q(0,1)  (af0 from P1, bf j1 from P3 -- both live)
        cp16(Bg + (size_t)bp4a * 8 * KD + ko, (char*)Bs + sb + bp4a * 1024);
        cp16(Bg + (size_t)bp4b * 8 * KD + ko, (char*)Bs + sb + bp4b * 1024);
        VMC(4);
        BAR;
        MFMAQ(0, 1, af0, bf);
    }
    // tail: K-tile 63 in buf1 (staged during kt=62), drain 4->2->0
    {
        const int cb = 32768;
        bf16x8 af0[4][2], af1[4][2], bf[2][2];
        RD_AF(af0, 0, cb)
        RD_BF(bf, 0, cb)
        VMC(2);                 // drains prev set3 (tail-P2 data)
        BAR;
        LGKM0;
        MFMAQ(0, 0, af0, bf);
        RD_AF(af1, 1, cb)
        VMC(0);                 // drains prev set4 (tail-P3 data)
        BAR;
        LGKM0;
        MFMAQ(1, 0, af1, bf);
        RD_BF(bf, 1, cb)
        LGKM0;
        MFMAQ(1, 1, af1, bf);
        MFMAQ(0, 1, af0, bf);
    }

    // epilogue: C/D layout col=lane&15, row=(lane>>4)*4+reg
    const int cm = (lane >> 4) << 2;
    const int cn = lane & 15;
#pragma unroll
    for (int j = 0; j < 4; ++j) {
        const int n = n0 + wn * 64 + j * 16 + cn;
        const float bv = bias[n];
#pragma unroll
        for (int i = 0; i < 8; ++i) {
            float* dst = C + (size_t)(m0 + wm * 128 + i * 16 + cm) * ND + n;
#pragma unroll
            for (int r = 0; r < 4; ++r)
                dst[(size_t)r * ND] = acc[i][j][r] + bv;
        }
    }
}

// ---------------------------------------------------------------------------
extern "C" void kernel_launch(void* const* d_in, const int* in_sizes, int n_in,
                              void* d_out, int out_size, void* d_ws, size_t ws_size,
                              hipStream_t stream) {
    const float* x    = (const float*)d_in[0];   // [M][K] fp32
    const int* qw     = (const int*)d_in[1];     // [N][K/2]
    const float* wsc  = (const float*)d_in[2];   // [K/64][N]
    const float* pd   = (const float*)d_in[3];   // [R][K]
    const float* pu   = (const float*)d_in[4];   // [N][R]
    const float* wts  = (const float*)d_in[5];   // [1]
    const float* bias = (const float*)d_in[6];   // [N]
    float* out = (float*)d_out;                  // [M][N] fp32

    __hip_bfloat16* weff = (__hip_bfloat16*)d_ws;
    __hip_bfloat16* xbf  = (__hip_bfloat16*)((char*)d_ws + (size_t)ND * KD * sizeof(__hip_bfloat16));

    cvt_x<<<(MD * (size_t)KD) / (256 * 8), 256, 0, stream>>>(x, xbf);
    build_weff<<<dim3(KD / 128, ND / 64), 256, 0, stream>>>(qw, wsc, pd, pu, wts, weff);
    gemm_bt_bias<<<512, 512, 0, stream>>>(xbf, weff, bias, out);
}